// Round 21
// baseline (203.282 us; speedup 1.0000x reference)
//
#include <hip/hip_runtime.h>
#include <hip/hip_bf16.h>

// Problem constants (reference file)
#define NN 50000
#define F_IN 512
#define HH 128
#define CC 64
#define NBUK 49                       // ceil(NN / 1024) row buckets

typedef __attribute__((ext_vector_type(8))) short short8v;   // 8 bf16 (4 VGPRs)
typedef __attribute__((ext_vector_type(4))) float f32x4;     // MFMA accumulator
typedef __attribute__((ext_vector_type(2))) float f32x2;

__device__ __forceinline__ short f2b(float f) {
    unsigned u = __builtin_bit_cast(unsigned, f);
    unsigned r = (u + 0x7fffu + ((u >> 16) & 1u)) >> 16;     // RNE
    return (short)r;
}
__device__ __forceinline__ float b2f(short s) {
    unsigned u = ((unsigned)(unsigned short)s) << 16;
    return __builtin_bit_cast(float, u);
}
__device__ __forceinline__ float b2f_lo(unsigned p) {
    return __builtin_bit_cast(float, p << 16);
}
__device__ __forceinline__ float b2f_hi(unsigned p) {
    return __builtin_bit_cast(float, p & 0xffff0000u);
}

// fp8 e4m3 (OCP) decode via gfx950 HW converts
__device__ __forceinline__ f32x2 q2_lo(unsigned p) {   // bytes 0,1
    return __builtin_amdgcn_cvt_pk_f32_fp8(p, false);
}
__device__ __forceinline__ f32x2 q2_hi(unsigned p) {   // bytes 2,3
    return __builtin_amdgcn_cvt_pk_f32_fp8(p, true);
}

// Bijective XCD swizzle (m204)
__device__ __forceinline__ int xcd_swz(int bid, int nwg) {
    int q = nwg >> 3, r = nwg & 7;
    int xcd = bid & 7, off = bid >> 3;
    return (xcd < r ? xcd * (q + 1) : r * (q + 1) + (xcd - r) * q) + off;
}

// async global->LDS, 16 B per lane
__device__ __forceinline__ void load_lds16(const short* g, short* l) {
    __builtin_amdgcn_global_load_lds(
        (const __attribute__((address_space(1))) unsigned int*)g,
        (__attribute__((address_space(3))) unsigned int*)l,
        16, 0, 0);
}

// ---------------------------------------------------------------------------
// Weight prep body: interleaved column-tiles.
// ---------------------------------------------------------------------------
template <int K, int OUTW>
__device__ __forceinline__ void wprep_body(const float* __restrict__ W0,
                                           const float* __restrict__ W1,
                                           const float* __restrict__ W2,
                                           short* __restrict__ Bt, int id) {
    const int nth = 3 * OUTW * (K / 8);
    if (id >= nth) return;
    const int n = id / (K / 8);
    const int kq = id % (K / 8);
    constexpr int HB = OUTW / 2;
    const int t = n / OUTW;
    const int r = n % OUTW;
    int sel, c;
    if (t < 2) { sel = (r >= HB) ? 1 : 0; c = t * HB + (r % HB); }
    else       { sel = 2; c = r; }
    const float* W = sel == 0 ? W0 : (sel == 1 ? W1 : W2);
    short v[8];
#pragma unroll
    for (int j = 0; j < 8; ++j) v[j] = f2b(W[(size_t)(kq * 8 + j) * OUTW + c]);
#pragma unroll
    for (int j = 0; j < 8; ++j) Bt[(size_t)n * K + kq * 8 + j] = v[j];
}

// ---------------------------------------------------------------------------
// prep0: zero_counts + wprep(L1) + wprep(L2) in one launch
// ---------------------------------------------------------------------------
__global__ __launch_bounds__(256) void prep0(int* __restrict__ counts, int n,
                                             const float* __restrict__ Wl,
                                             const float* __restrict__ Wh,
                                             const float* __restrict__ Wm,
                                             short* __restrict__ Bt1,
                                             const float* __restrict__ Wl2,
                                             const float* __restrict__ Wh2,
                                             const float* __restrict__ Wm2,
                                             short* __restrict__ Bt2,
                                             int nZero, int nW1) {
    const int b = blockIdx.x;
    if (b < nZero) {
        int i = b * 256 + threadIdx.x;
        if (i < n) counts[i] = 0;
    } else if (b < nZero + nW1) {
        wprep_body<F_IN, HH>(Wl, Wh, Wm, Bt1, (b - nZero) * 256 + threadIdx.x);
    } else {
        wprep_body<HH, CC>(Wl2, Wh2, Wm2, Bt2, (b - nZero - nW1) * 256 + threadIdx.x);
    }
}

// ---------------------------------------------------------------------------
// hist_xconv: histogram atomics interleaved under BW-bound xconv (Bresenham)
// ---------------------------------------------------------------------------
__global__ __launch_bounds__(256) void hist_xconv(const int* __restrict__ erow,
                                                  int* __restrict__ counts, int E,
                                                  const float* __restrict__ x,
                                                  short* __restrict__ xb, int n8,
                                                  int nHist) {
    const int b = blockIdx.x;
    const int total = gridDim.x;
    const long hb4 = ((long)b * nHist) / total;
    const long ha4 = ((long)(b + 1) * nHist) / total;
    if (ha4 != hb4) {
        int i = (int)hb4 * 256 + threadIdx.x;
        if (i < E) atomicAdd(&counts[erow[i]], 1);
        return;
    }
    int i = (b - (int)hb4) * 256 + threadIdx.x;
    if (i >= n8) return;
    const float4* xp = (const float4*)x;
    const float4 a = xp[2 * i];
    const float4 bb = xp[2 * i + 1];
    short8v o;
    o[0] = f2b(a.x); o[1] = f2b(a.y); o[2] = f2b(a.z); o[3] = f2b(a.w);
    o[4] = f2b(bb.x); o[5] = f2b(bb.y); o[6] = f2b(bb.z); o[7] = f2b(bb.w);
    *reinterpret_cast<short8v*>(&xb[(size_t)i * 8]) = o;
}

// ---------------------------------------------------------------------------
// GEMM body: double-buffered BK=32 pipeline, counted vmcnt across raw
// barriers (r17 configuration — best measured).
// ---------------------------------------------------------------------------
template <int K, int BNout>
__device__ __forceinline__ void gemm_body(const short* __restrict__ A,
                                          const short* __restrict__ Bt,
                                          unsigned* __restrict__ xq,
                                          short* __restrict__ xh,
                                          short* __restrict__ xm,
                                          int M, int wg, short* smem) {
    constexpr int BM = 128, BK = 32;
    constexpr int FM = (BNout == 128) ? 4 : 2;
    constexpr int FN = 4;
    constexpr int WM = FM * 16;
    constexpr int NKT = K / BK;
    constexpr int AW = (BM * BK / 512) / 4;       // A gll per wave (2)
    constexpr int BW_ = (BNout * BK / 512) / 4;   // B gll per wave (2 or 1)
    constexpr int VMC = AW + BW_;                 // per-tile in-flight per wave
    constexpr int HALF = BM * BK + BNout * BK;    // shorts per buffer
    constexpr int HB = BNout / 2;

    const int tid = threadIdx.x;
    const int lane = tid & 63;
    const int wid = tid >> 6;
    const int bm = wg / 3;
    const int bn = wg % 3;
    const int m0 = bm * BM;
    const int n0 = bn * BNout;
    const int wm = (BNout == 128) ? (wid >> 1) : wid;
    const int wn = (BNout == 128) ? (wid & 1) : 0;

    const int rl = lane >> 2;                     // row-within-chunk 0..15
    const int sl = (lane & 3) ^ ((lane >> 3) & 3);  // source slot (bank swizzle)

    f32x4 acc[FM][FN];
#pragma unroll
    for (int i = 0; i < FM; ++i)
#pragma unroll
        for (int j = 0; j < FN; ++j) acc[i][j] = (f32x4){0.f, 0.f, 0.f, 0.f};

    auto issue = [&](int kt, int b) {
        const int k0 = kt * BK;
        short* As = smem + b * HALF;
        short* Bs = As + BM * BK;
#pragma unroll
        for (int i = 0; i < AW; ++i) {
            int g = wid * AW + i;
            int r = g * 16 + rl;
            int gr = m0 + r; if (gr >= M) gr = M - 1;
            load_lds16(&A[(size_t)gr * K + k0 + sl * 8], &As[g * 512]);
        }
#pragma unroll
        for (int i = 0; i < BW_; ++i) {
            int g = wid * BW_ + i;
            int r = g * 16 + rl;
            load_lds16(&Bt[(size_t)(n0 + r) * K + k0 + sl * 8], &Bs[g * 512]);
        }
    };

    issue(0, 0);

    const int mrow = lane & 15;
    const int kg = lane >> 4;                     // 0..3
    for (int kt = 0; kt < NKT; ++kt) {
        const int cur = kt & 1;
        if (kt + 1 < NKT) {
            issue(kt + 1, cur ^ 1);
            asm volatile("s_waitcnt vmcnt(%0)" :: "n"(VMC) : "memory");
        } else {
            asm volatile("s_waitcnt vmcnt(0)" ::: "memory");
        }
        __builtin_amdgcn_s_barrier();
        __builtin_amdgcn_sched_barrier(0);

        const short* As = smem + cur * HALF;
        const short* Bs = As + BM * BK;
        short8v af[FM], bf[FN];
#pragma unroll
        for (int f = 0; f < FM; ++f) {
            int m = wm * WM + f * 16 + mrow;
            af[f] = *reinterpret_cast<const short8v*>(
                &As[m * 32 + ((kg ^ ((m >> 1) & 3)) << 3)]);
        }
#pragma unroll
        for (int f = 0; f < FN; ++f) {
            int nr = wn * 64 + f * 16 + mrow;
            bf[f] = *reinterpret_cast<const short8v*>(
                &Bs[nr * 32 + ((kg ^ ((nr >> 1) & 3)) << 3)]);
        }
#pragma unroll
        for (int i = 0; i < FM; ++i)
#pragma unroll
            for (int j = 0; j < FN; ++j)
                acc[i][j] = __builtin_amdgcn_mfma_f32_16x16x32_bf16(
                    af[i], bf[j], acc[i][j], 0, 0, 0);

        asm volatile("s_waitcnt lgkmcnt(0)" ::: "memory");
        __builtin_amdgcn_sched_barrier(0);
        __builtin_amdgcn_s_barrier();
    }

    // ---- stage accumulator tile into LDS (bf16) ----
#pragma unroll
    for (int i = 0; i < FM; ++i)
#pragma unroll
        for (int j = 0; j < FN; ++j) {
            int cc = wn * 64 + j * 16 + (lane & 15);
#pragma unroll
            for (int e = 0; e < 4; ++e) {
                int r = wm * WM + i * 16 + (lane >> 4) * 4 + e;
                smem[r * BNout + cc] = f2b(acc[i][j][e]);
            }
        }
    __syncthreads();

    if (bn == 2) {
        constexpr int CH = BM * BNout / 8;
#pragma unroll
        for (int p = 0; p < CH / 256; ++p) {
            int idx = p * 256 + tid;
            int r = idx / (BNout / 8);
            int c8 = idx % (BNout / 8);
            int grow = m0 + r;
            if (grow < M)
                *reinterpret_cast<int4*>(&xm[(size_t)grow * BNout + c8 * 8]) =
                    *reinterpret_cast<const int4*>(&smem[r * BNout + c8 * 8]);
        }
    } else {
#pragma unroll
        for (int p = 0; p < (BM * (HB / 8)) / 256; ++p) {
            int idx = p * 256 + tid;
            int r = idx / (HB / 8);
            int c8 = idx % (HB / 8);
            int grow = m0 + r;
            if (grow < M)
                *reinterpret_cast<int4*>(&xh[(size_t)grow * BNout + bn * HB + c8 * 8]) =
                    *reinterpret_cast<const int4*>(&smem[r * BNout + HB + c8 * 8]);
        }
#pragma unroll
        for (int p = 0; p < (BM * (BNout / 4)) / 256; ++p) {
            int idx = p * 256 + tid;
            int r = idx / (BNout / 4);
            int k = idx % (BNout / 4);
            int grow = m0 + r;
            if (grow < M) {
                unsigned lw = *reinterpret_cast<const unsigned*>(&smem[r * BNout + 2 * k]);
                unsigned hw = *reinterpret_cast<const unsigned*>(&smem[r * BNout + HB + 2 * k]);
                unsigned w;
                if (BNout == 128) {
                    w = __builtin_amdgcn_cvt_pk_fp8_f32(b2f_lo(lw), b2f_hi(lw), 0, false);
                    w = __builtin_amdgcn_cvt_pk_fp8_f32(b2f_lo(hw), b2f_hi(hw), w, true);
                } else {
                    w = __builtin_amdgcn_cvt_pk_fp8_f32(b2f_lo(lw), b2f_lo(hw), 0, false);
                    w = __builtin_amdgcn_cvt_pk_fp8_f32(b2f_hi(lw), b2f_hi(hw), w, true);
                }
                xq[(size_t)grow * (BNout / 2) + bn * (BNout / 4) + k] = w;
            }
        }
    }
}

template <int BNout>
struct GemmSmem {
    static constexpr int SM1 = 2 * (128 * 32 + BNout * 32);
    static constexpr int SM2 = 128 * BNout;
    static constexpr int SZ = SM1 > SM2 ? SM1 : SM2;
};

// ---------------------------------------------------------------------------
// Fused layer-1 GEMM + sort pass 1 (bucket-binning of edges into tmp).
// Pass-1 block: 2048 edges; LDS per-bucket counts; one global atomicAdd per
// bucket reserves a contiguous run in tmp; 8B records written coalesced.
// ---------------------------------------------------------------------------
template <int K, int BNout>
__global__ __launch_bounds__(256) void gemm_scatter(const short* __restrict__ A,
                                                    const short* __restrict__ Bt,
                                                    unsigned* __restrict__ xq,
                                                    short* __restrict__ xh,
                                                    short* __restrict__ xm,
                                                    int M, int nGemm,
                                                    const int* __restrict__ row,
                                                    const int* __restrict__ col,
                                                    const float* __restrict__ val,
                                                    int* __restrict__ gcur,
                                                    int2* __restrict__ tmp, int E,
                                                    int nScat) {
    __shared__ short smem[GemmSmem<BNout>::SZ];

    const int total = nGemm + nScat;
    const int swz = xcd_swz(blockIdx.x, total);
    const long ns_b = ((long)swz * nScat) / total;
    const long ns_a = ((long)(swz + 1) * nScat) / total;

    if (ns_a != ns_b) {
        // ---- sort pass 1: bin 2048 edges by row>>10 into tmp ----
        int* icnt = reinterpret_cast<int*>(smem);          // [64] counts
        int* ibase = icnt + 64;                            // [64] run bases
        const int tid = threadIdx.x;
        if (tid < 64) icnt[tid] = 0;
        __syncthreads();

        const int e0 = (int)ns_b * 2048;
        int rr[8], cc[8], slot[8], bk[8];
        float vv[8];
#pragma unroll
        for (int q = 0; q < 8; ++q) {
            int i = e0 + q * 256 + tid;
            if (i < E) {
                rr[q] = row[i];
                cc[q] = col[i];
                vv[q] = val[i];
                bk[q] = rr[q] >> 10;
                slot[q] = atomicAdd(&icnt[bk[q]], 1);
            } else {
                bk[q] = -1;
            }
        }
        __syncthreads();
        if (tid < 64) {
            int c = icnt[tid];
            ibase[tid] = (c > 0) ? atomicAdd(&gcur[tid], c) : 0;
        }
        __syncthreads();
#pragma unroll
        for (int q = 0; q < 8; ++q) {
            if (bk[q] >= 0) {
                int2 rec;
                rec.x = rr[q] | (cc[q] << 16);
                rec.y = __builtin_bit_cast(int, vv[q]);
                tmp[ibase[bk[q]] + slot[q]] = rec;
            }
        }
        return;
    }
    gemm_body<K, BNout>(A, Bt, xq, xh, xm, M, swz - (int)ns_b, smem);
}

// ---------------------------------------------------------------------------
// Sort pass 2: per bucket (1024 rows), scatter tmp records to final CSR
// positions via LDS per-row cursors. All stores land in the bucket's ~65KB
// L2-resident window -> no line-RMW amplification.
// ---------------------------------------------------------------------------
__global__ __launch_bounds__(1024) void sort_pass2(const int* __restrict__ rowptr,
                                                   const int2* __restrict__ tmp,
                                                   unsigned* __restrict__ edges,
                                                   int n) {
    __shared__ int cur[1024];
    const int b = blockIdx.x;
    const int row0 = b << 10;
    const int nrows = min(1024, n - row0);
    const int tid = threadIdx.x;
    if (tid < nrows) cur[tid] = rowptr[row0 + tid];
    __syncthreads();

    const int start = rowptr[row0];
    const int end = rowptr[min(row0 + 1024, n)];
    for (int i = start + tid; i < end; i += 1024) {
        const int2 rec = tmp[i];
        const int rl = rec.x & 0xffff;
        const int cc = ((unsigned)rec.x) >> 16;
        const float v = __builtin_bit_cast(float, rec.y);
        const int p = atomicAdd(&cur[rl & 1023], 1);
        edges[p] = (unsigned)cc | ((unsigned)(unsigned short)f2b(v) << 16);
    }
}

// ---------------------------------------------------------------------------
// Standalone layer-2 GEMM
// ---------------------------------------------------------------------------
template <int K, int BNout>
__global__ __launch_bounds__(256) void gemm_mfma(const short* __restrict__ A,
                                                 const short* __restrict__ Bt,
                                                 unsigned* __restrict__ xq,
                                                 short* __restrict__ xh,
                                                 short* __restrict__ xm,
                                                 int M) {
    __shared__ short smem[GemmSmem<BNout>::SZ];
    gemm_body<K, BNout>(A, Bt, xq, xh, xm, M, xcd_swz(blockIdx.x, gridDim.x), smem);
}

// ---------------------------------------------------------------------------
// CSR scan chain
// ---------------------------------------------------------------------------
__global__ __launch_bounds__(256) void block_sums_kernel(const int* __restrict__ counts,
                                                         int* __restrict__ bsums, int n) {
    __shared__ int s[256];
    int tid = threadIdx.x;
    int i = blockIdx.x * 256 + tid;
    s[tid] = (i < n) ? counts[i] : 0;
    __syncthreads();
#pragma unroll
    for (int off = 128; off > 0; off >>= 1) {
        if (tid < off) s[tid] += s[tid + off];
        __syncthreads();
    }
    if (tid == 0) bsums[blockIdx.x] = s[0];
}

__global__ __launch_bounds__(256) void scan_bsums_kernel(int* __restrict__ bsums, int nb) {
    __shared__ int s[256];
    int t = threadIdx.x;
    int v = (t < nb) ? bsums[t] : 0;
    s[t] = v;
    __syncthreads();
#pragma unroll
    for (int off = 1; off < 256; off <<= 1) {
        int u = (t >= off) ? s[t - off] : 0;
        __syncthreads();
        s[t] += u;
        __syncthreads();
    }
    if (t < nb) bsums[t] = s[t] - v;      // exclusive
}

__global__ __launch_bounds__(256) void scan_final_kernel(const int* __restrict__ counts,
                                                         const int* __restrict__ bsums,
                                                         int* __restrict__ rowptr,
                                                         int* __restrict__ gcur, int n) {
    __shared__ int s[256];
    int tid = threadIdx.x;
    int i = blockIdx.x * 256 + tid;
    int v = (i < n) ? counts[i] : 0;
    s[tid] = v;
    __syncthreads();
#pragma unroll
    for (int off = 1; off < 256; off <<= 1) {
        int t = (tid >= off) ? s[tid - off] : 0;
        __syncthreads();
        s[tid] += t;
        __syncthreads();
    }
    int excl = s[tid] - v + bsums[blockIdx.x];
    if (i < n) {
        rowptr[i] = excl;
        if ((i & 1023) == 0) gcur[i >> 10] = excl;   // bucket run cursors
        if (i == n - 1) rowptr[n] = excl + v;
    }
}

// ---------------------------------------------------------------------------
__device__ __forceinline__ float wave_sum(float v) {
#pragma unroll
    for (int off = 32; off > 0; off >>= 1) v += __shfl_xor(v, off, 64);
    return v;
}
__device__ __forceinline__ float wave_max(float v) {
#pragma unroll
    for (int off = 32; off > 0; off >>= 1) v = fmaxf(v, __shfl_xor(v, off, 64));
    return v;
}

// ---------------------------------------------------------------------------
// Layer-1 fused: dual CSR spmm (fp8 gathers, 8-deep pipeline, 4B edge recs)
// + attention + combine -> h bf16.
// ---------------------------------------------------------------------------
__global__ __launch_bounds__(256) void spmm_att1(const int* __restrict__ rowptr,
                                                 const unsigned* __restrict__ edges,
                                                 const unsigned* __restrict__ xq,
                                                 const unsigned* __restrict__ xhp,
                                                 const unsigned* __restrict__ xmp,
                                                 const float* __restrict__ a_low,
                                                 const float* __restrict__ a_high,
                                                 const float* __restrict__ a_mlp,
                                                 const float* __restrict__ av,
                                                 short* __restrict__ hb,
                                                 int n) {
    const int node = blockIdx.x * 4 + (threadIdx.x >> 6);
    const int lane = threadIdx.x & 63;
    if (node >= n) return;

    const int s = __builtin_amdgcn_readfirstlane(rowptr[node]);
    const int e = __builtin_amdgcn_readfirstlane(rowptr[node + 1]);

    float l0 = 0.f, l1 = 0.f, h0 = 0.f, h1 = 0.f;
    for (int j = s; j < e; j += 8) {
        int   cq[8];
        float vq[8];
#pragma unroll
        for (int q = 0; q < 8; ++q) {
            const int jj = min(j + q, e - 1);
            const unsigned rec = __builtin_amdgcn_readfirstlane(edges[jj]);
            cq[q] = (int)(rec & 0xffffu);
            float t = b2f((short)(rec >> 16));
            vq[q] = (j + q < e) ? t : 0.f;
        }
        unsigned p[8];
#pragma unroll
        for (int q = 0; q < 8; ++q)
            p[q] = xq[(size_t)cq[q] * 64 + lane];      // 8 gathers in flight
#pragma unroll
        for (int q = 0; q < 8; ++q) {
            const f32x2 lo = q2_lo(p[q]);
            const f32x2 hi = q2_hi(p[q]);
            l0 += vq[q] * lo.x; l1 += vq[q] * lo.y;
            h0 += vq[q] * hi.x; h1 += vq[q] * hi.y;
        }
    }

    const unsigned xhn = xhp[(size_t)node * 64 + lane];
    const unsigned xmn = xmp[(size_t)node * 64 + lane];
    float ol0 = fmaxf(l0, 0.f);
    float ol1 = fmaxf(l1, 0.f);
    float oh0 = fmaxf(b2f_lo(xhn) - h0, 0.f);
    float oh1 = fmaxf(b2f_hi(xhn) - h1, 0.f);
    float om0 = fmaxf(b2f_lo(xmn), 0.f);
    float om1 = fmaxf(b2f_hi(xmn), 0.f);

    const float2 aL = ((const float2*)a_low)[lane];
    const float2 aH = ((const float2*)a_high)[lane];
    const float2 aM = ((const float2*)a_mlp)[lane];
    float dl = wave_sum(ol0 * aL.x + ol1 * aL.y);
    float dh = wave_sum(oh0 * aH.x + oh1 * aH.y);
    float dm = wave_sum(om0 * aM.x + om1 * aM.y);

    const float g0 = 1.f / (1.f + expf(-dl));
    const float g1 = 1.f / (1.f + expf(-dh));
    const float g2 = 1.f / (1.f + expf(-dm));
    float s0 = (g0 * av[0] + g1 * av[3] + g2 * av[6]) * (1.f / 3.f);
    float s1 = (g0 * av[1] + g1 * av[4] + g2 * av[7]) * (1.f / 3.f);
    float s2 = (g0 * av[2] + g1 * av[5] + g2 * av[8]) * (1.f / 3.f);
    float mx = fmaxf(s0, fmaxf(s1, s2));
    float e0 = expf(s0 - mx), e1 = expf(s1 - mx), e2 = expf(s2 - mx);
    float inv = 1.f / (e0 + e1 + e2);
    float at0 = e0 * inv, at1 = e1 * inv, at2 = e2 * inv;

    float ho0 = 3.f * (at0 * ol0 + at1 * oh0 + at2 * om0);
    float ho1 = 3.f * (at0 * ol1 + at1 * oh1 + at2 * om1);
    unsigned pk = (unsigned)(unsigned short)f2b(ho0) |
                  ((unsigned)(unsigned short)f2b(ho1) << 16);
    ((unsigned*)hb)[(size_t)node * 64 + lane] = pk;
}

// ---------------------------------------------------------------------------
// Layer-2 fused: dual CSR spmm (fp8 ushort gathers, 8-deep, 4B edge recs)
// + attention + combine + log_softmax -> out.
// ---------------------------------------------------------------------------
__global__ __launch_bounds__(256) void spmm_att2(const int* __restrict__ rowptr,
                                                 const unsigned* __restrict__ edges,
                                                 const unsigned short* __restrict__ xq,
                                                 const short* __restrict__ xhp,
                                                 const short* __restrict__ xmp,
                                                 const float* __restrict__ a_low,
                                                 const float* __restrict__ a_high,
                                                 const float* __restrict__ a_mlp,
                                                 const float* __restrict__ av,
                                                 float* __restrict__ out,
                                                 int n) {
    const int node = blockIdx.x * 4 + (threadIdx.x >> 6);
    const int lane = threadIdx.x & 63;
    if (node >= n) return;

    const int s = __builtin_amdgcn_readfirstlane(rowptr[node]);
    const int e = __builtin_amdgcn_readfirstlane(rowptr[node + 1]);

    float accl = 0.f, acch = 0.f;
    for (int j = s; j < e; j += 8) {
        int   cq[8];
        float vq[8];
#pragma unroll
        for (int q = 0; q < 8; ++q) {
            const int jj = min(j + q, e - 1);
            const unsigned rec = __builtin_amdgcn_readfirstlane(edges[jj]);
            cq[q] = (int)(rec & 0xffffu);
            float t = b2f((short)(rec >> 16));
            vq[q] = (j + q < e) ? t : 0.f;
        }
        unsigned short p[8];
#pragma unroll
        for (int q = 0; q < 8; ++q)
            p[q] = xq[(size_t)cq[q] * 64 + lane];
#pragma unroll
        for (int q = 0; q < 8; ++q) {
            const f32x2 d = q2_lo((unsigned)p[q]);
            accl += vq[q] * d.x;
            acch += vq[q] * d.y;
        }
    }

    float ol = fmaxf(accl, 0.f);
    float oh = fmaxf(b2f(xhp[(size_t)node * 64 + lane]) - acch, 0.f);
    float om = fmaxf(b2f(xmp[(size_t)node * 64 + lane]), 0.f);

    float dl = wave_sum(ol * a_low[lane]);
    float dh = wave_sum(oh * a_high[lane]);
    float dm = wave_sum(om * a_mlp[lane]);

    const float g0 = 1.f / (1.f + expf(-dl));
    const float g1 = 1.f / (1.f + expf(-dh));
    const float g2 = 1.f / (1.f + expf(-dm));
    float s0 = (g0 * av[0] + g1 * av[3] + g2 * av[6]) * (1.f / 3.f);
    float s1 = (g0 * av[1] + g1 * av[4] + g2 * av[7]) * (1.f / 3.f);
    float s2 = (g0 * av[2] + g1 * av[5] + g2 * av[8]) * (1.f / 3.f);
    float mx3 = fmaxf(s0, fmaxf(s1, s2));
    float e0 = expf(s0 - mx3), e1 = expf(s1 - mx3), e2 = expf(s2 - mx3);
    float inv = 1.f / (e0 + e1 + e2);
    float at0 = e0 * inv, at1 = e1 * inv, at2 = e2 * inv;

    float o = 3.f * (at0 * ol + at1 * oh + at2 * om);

    float m = wave_max(o);
    float ex = expf(o - m);
    float su = wave_sum(ex);
    out[(size_t)node * 64 + lane] = o - m - logf(su);
}

// ---------------------------------------------------------------------------
extern "C" void kernel_launch(void* const* d_in, const int* in_sizes, int n_in,
                              void* d_out, int out_size, void* d_ws, size_t ws_size,
                              hipStream_t stream) {
    const float* x    = (const float*)d_in[0];
    const int*   erow = (const int*)d_in[1];
    const int*   ecol = (const int*)d_in[2];
    const float* eval = (const float*)d_in[3];
    const float* Wl   = (const float*)d_in[4];
    const float* Wh   = (const float*)d_in[5];
    const float* Wm   = (const float*)d_in[6];
    const float* al   = (const float*)d_in[7];
    const float* ah   = (const float*)d_in[8];
    const float* am   = (const float*)d_in[9];
    const float* av   = (const float*)d_in[10];
    const float* Wl2  = (const float*)d_in[11];
    const float* Wh2  = (const float*)d_in[12];
    const float* Wm2  = (const float*)d_in[13];
    const float* al2  = (const float*)d_in[14];
    const float* ah2  = (const float*)d_in[15];
    const float* am2  = (const float*)d_in[16];
    const float* av2  = (const float*)d_in[17];
    float* out = (float*)d_out;

    const int E = in_sizes[1];
    const int N = NN;

    short* ws    = (short*)d_ws;
    short* xb    = ws;                          // N*512 bf16 (converted x)
    short* xh1   = xb + (size_t)N * 512;        // N*128 bf16 plane
    short* xm1   = xh1 + (size_t)N * 128;       // N*128 bf16 plane
    short* hb    = xm1 + (size_t)N * 128;       // N*128 bf16
    unsigned* xq1 = (unsigned*)(hb + (size_t)N * 128);   // N*64 dwords (12.8 MB)
    short* Bt1   = (short*)(xq1 + (size_t)N * 64);       // 384*512
    short* Bt2   = Bt1 + 384 * 512;             // 192*128
    int*   ip    = (int*)(Bt2 + 192 * 128);
    int*   counts = ip;                         // N
    int*   rowptr = ip + N;                     // N+1
    int*   gcur   = ip + 2 * N + 1;             // 64 bucket cursors
    int*   bsums  = ip + 2 * N + 1 + 64;        // 256
    unsigned* edges = (unsigned*)(ip + 2 * N + 1 + 64 + 256);  // E dwords
    int2*  tmp   = (int2*)(((size_t)(edges + E) + 15) & ~(size_t)15);  // E int2

    // Layer-2 aliases (xh1/xm1/xq1 dead after spmm_att1)
    unsigned* xq2 = xq1;                        // N*32 dwords (N*64 fp8 ushorts)
    short* xh2 = xh1;                           // N*64 bf16
    short* xm2 = xh1 + (size_t)N * 64;          // N*64 bf16

    const int NB = (N + 255) / 256;
    const int EB = (E + 255) / 256;
    const int node_blocks = (N + 3) / 4;
    const int MT = (N + 127) / 128;
    const int XCB = (N * F_IN / 8 + 255) / 256;
    const int W1B = (3 * HH * (F_IN / 8) + 255) / 256;
    const int W2B = (3 * CC * (HH / 8) + 255) / 256;
    const int nGemm1 = MT * 3;
    const int nScat = (E + 2047) / 2048;        // pass-1 blocks (2048 edges each)

    // ---------------- prep (fused) + CSR scan chain ----------------
    prep0<<<NB + W1B + W2B, 256, 0, stream>>>(counts, N, Wl, Wh, Wm, Bt1,
                                              Wl2, Wh2, Wm2, Bt2, NB, W1B);
    hist_xconv<<<EB + XCB, 256, 0, stream>>>(erow, counts, E, x, xb,
                                             N * F_IN / 8, EB);
    block_sums_kernel<<<NB, 256, 0, stream>>>(counts, bsums, N);
    scan_bsums_kernel<<<1, 256, 0, stream>>>(bsums, NB);
    scan_final_kernel<<<NB, 256, 0, stream>>>(counts, bsums, rowptr, gcur, N);

    // ---------------- Layer 1 (gemm interleaved with sort pass 1) ----------
    gemm_scatter<F_IN, HH><<<nGemm1 + nScat, 256, 0, stream>>>(
        xb, Bt1, xq1, xh1, xm1, N, nGemm1, erow, ecol, eval, gcur, tmp, E, nScat);
    sort_pass2<<<NBUK, 1024, 0, stream>>>(rowptr, tmp, edges, N);
    spmm_att1<<<node_blocks, 256, 0, stream>>>(rowptr, edges, xq1,
                                               (const unsigned*)xh1,
                                               (const unsigned*)xm1,
                                               al, ah, am, av, hb, N);

    // ---------------- Layer 2 ----------------
    gemm_mfma<HH, CC><<<MT * 3, 256, 0, stream>>>(hb, Bt2, xq2, xh2, xm2, N);
    spmm_att2<<<node_blocks, 256, 0, stream>>>(rowptr, edges,
                                               (const unsigned short*)xq2,
                                               xh2, xm2,
                                               al2, ah2, am2, av2, out, N);
}

// Round 22
// 194.262 us; speedup vs baseline: 1.0464x; 1.0464x over previous
//
#include <hip/hip_runtime.h>
#include <hip/hip_bf16.h>

// Problem constants (reference file)
#define NN 50000
#define F_IN 512
#define HH 128
#define CC 64

typedef __attribute__((ext_vector_type(8))) short short8v;   // 8 bf16 (4 VGPRs)
typedef __attribute__((ext_vector_type(4))) float f32x4;     // MFMA accumulator
typedef __attribute__((ext_vector_type(2))) float f32x2;

__device__ __forceinline__ short f2b(float f) {
    unsigned u = __builtin_bit_cast(unsigned, f);
    unsigned r = (u + 0x7fffu + ((u >> 16) & 1u)) >> 16;     // RNE
    return (short)r;
}
__device__ __forceinline__ float b2f(short s) {
    unsigned u = ((unsigned)(unsigned short)s) << 16;
    return __builtin_bit_cast(float, u);
}
__device__ __forceinline__ float b2f_lo(unsigned p) {
    return __builtin_bit_cast(float, p << 16);
}
__device__ __forceinline__ float b2f_hi(unsigned p) {
    return __builtin_bit_cast(float, p & 0xffff0000u);
}

// fp8 e4m3 (OCP) decode via gfx950 HW converts
__device__ __forceinline__ f32x2 q2_lo(unsigned p) {   // bytes 0,1
    return __builtin_amdgcn_cvt_pk_f32_fp8(p, false);
}
__device__ __forceinline__ f32x2 q2_hi(unsigned p) {   // bytes 2,3
    return __builtin_amdgcn_cvt_pk_f32_fp8(p, true);
}

// Bijective XCD swizzle (m204)
__device__ __forceinline__ int xcd_swz(int bid, int nwg) {
    int q = nwg >> 3, r = nwg & 7;
    int xcd = bid & 7, off = bid >> 3;
    return (xcd < r ? xcd * (q + 1) : r * (q + 1) + (xcd - r) * q) + off;
}

// async global->LDS, 16 B per lane
__device__ __forceinline__ void load_lds16(const short* g, short* l) {
    __builtin_amdgcn_global_load_lds(
        (const __attribute__((address_space(1))) unsigned int*)g,
        (__attribute__((address_space(3))) unsigned int*)l,
        16, 0, 0);
}

// ---------------------------------------------------------------------------
// Weight prep body: interleaved column-tiles.
// ---------------------------------------------------------------------------
template <int K, int OUTW>
__device__ __forceinline__ void wprep_body(const float* __restrict__ W0,
                                           const float* __restrict__ W1,
                                           const float* __restrict__ W2,
                                           short* __restrict__ Bt, int id) {
    const int nth = 3 * OUTW * (K / 8);
    if (id >= nth) return;
    const int n = id / (K / 8);
    const int kq = id % (K / 8);
    constexpr int HB = OUTW / 2;
    const int t = n / OUTW;
    const int r = n % OUTW;
    int sel, c;
    if (t < 2) { sel = (r >= HB) ? 1 : 0; c = t * HB + (r % HB); }
    else       { sel = 2; c = r; }
    const float* W = sel == 0 ? W0 : (sel == 1 ? W1 : W2);
    short v[8];
#pragma unroll
    for (int j = 0; j < 8; ++j) v[j] = f2b(W[(size_t)(kq * 8 + j) * OUTW + c]);
#pragma unroll
    for (int j = 0; j < 8; ++j) Bt[(size_t)n * K + kq * 8 + j] = v[j];
}

// ---------------------------------------------------------------------------
// prep0: zero_counts + wprep(L1) + wprep(L2) in one launch
// ---------------------------------------------------------------------------
__global__ __launch_bounds__(256) void prep0(int* __restrict__ counts, int n,
                                             const float* __restrict__ Wl,
                                             const float* __restrict__ Wh,
                                             const float* __restrict__ Wm,
                                             short* __restrict__ Bt1,
                                             const float* __restrict__ Wl2,
                                             const float* __restrict__ Wh2,
                                             const float* __restrict__ Wm2,
                                             short* __restrict__ Bt2,
                                             int nZero, int nW1) {
    const int b = blockIdx.x;
    if (b < nZero) {
        int i = b * 256 + threadIdx.x;
        if (i < n) counts[i] = 0;
    } else if (b < nZero + nW1) {
        wprep_body<F_IN, HH>(Wl, Wh, Wm, Bt1, (b - nZero) * 256 + threadIdx.x);
    } else {
        wprep_body<HH, CC>(Wl2, Wh2, Wm2, Bt2, (b - nZero - nW1) * 256 + threadIdx.x);
    }
}

// ---------------------------------------------------------------------------
// hist_xconv: histogram atomics interleaved under BW-bound xconv (Bresenham)
// ---------------------------------------------------------------------------
__global__ __launch_bounds__(256) void hist_xconv(const int* __restrict__ erow,
                                                  int* __restrict__ counts, int E,
                                                  const float* __restrict__ x,
                                                  short* __restrict__ xb, int n8,
                                                  int nHist) {
    const int b = blockIdx.x;
    const int total = gridDim.x;
    const long hb4 = ((long)b * nHist) / total;
    const long ha4 = ((long)(b + 1) * nHist) / total;
    if (ha4 != hb4) {
        int i = (int)hb4 * 256 + threadIdx.x;
        if (i < E) atomicAdd(&counts[erow[i]], 1);
        return;
    }
    int i = (b - (int)hb4) * 256 + threadIdx.x;
    if (i >= n8) return;
    const float4* xp = (const float4*)x;
    const float4 a = xp[2 * i];
    const float4 bb = xp[2 * i + 1];
    short8v o;
    o[0] = f2b(a.x); o[1] = f2b(a.y); o[2] = f2b(a.z); o[3] = f2b(a.w);
    o[4] = f2b(bb.x); o[5] = f2b(bb.y); o[6] = f2b(bb.z); o[7] = f2b(bb.w);
    *reinterpret_cast<short8v*>(&xb[(size_t)i * 8]) = o;
}

// ---------------------------------------------------------------------------
// GEMM body: double-buffered BK=32 pipeline, counted vmcnt across raw
// barriers. Epilogue: LDS-staged; bn<2 writes xh bf16 half-plane + fp8
// gather words directly; bn==2 writes xm bf16 plane.
// ---------------------------------------------------------------------------
template <int K, int BNout>
__device__ __forceinline__ void gemm_body(const short* __restrict__ A,
                                          const short* __restrict__ Bt,
                                          unsigned* __restrict__ xq,
                                          short* __restrict__ xh,
                                          short* __restrict__ xm,
                                          int M, int wg, short* smem) {
    constexpr int BM = 128, BK = 32;
    constexpr int FM = (BNout == 128) ? 4 : 2;
    constexpr int FN = 4;
    constexpr int WM = FM * 16;
    constexpr int NKT = K / BK;
    constexpr int AW = (BM * BK / 512) / 4;       // A gll per wave (2)
    constexpr int BW_ = (BNout * BK / 512) / 4;   // B gll per wave (2 or 1)
    constexpr int VMC = AW + BW_;                 // per-tile in-flight per wave
    constexpr int HALF = BM * BK + BNout * BK;    // shorts per buffer
    constexpr int HB = BNout / 2;

    const int tid = threadIdx.x;
    const int lane = tid & 63;
    const int wid = tid >> 6;
    const int bm = wg / 3;
    const int bn = wg % 3;
    const int m0 = bm * BM;
    const int n0 = bn * BNout;
    const int wm = (BNout == 128) ? (wid >> 1) : wid;
    const int wn = (BNout == 128) ? (wid & 1) : 0;

    const int rl = lane >> 2;                     // row-within-chunk 0..15
    const int sl = (lane & 3) ^ ((lane >> 3) & 3);  // source slot (bank swizzle)

    f32x4 acc[FM][FN];
#pragma unroll
    for (int i = 0; i < FM; ++i)
#pragma unroll
        for (int j = 0; j < FN; ++j) acc[i][j] = (f32x4){0.f, 0.f, 0.f, 0.f};

    auto issue = [&](int kt, int b) {
        const int k0 = kt * BK;
        short* As = smem + b * HALF;
        short* Bs = As + BM * BK;
#pragma unroll
        for (int i = 0; i < AW; ++i) {
            int g = wid * AW + i;
            int r = g * 16 + rl;
            int gr = m0 + r; if (gr >= M) gr = M - 1;
            load_lds16(&A[(size_t)gr * K + k0 + sl * 8], &As[g * 512]);
        }
#pragma unroll
        for (int i = 0; i < BW_; ++i) {
            int g = wid * BW_ + i;
            int r = g * 16 + rl;
            load_lds16(&Bt[(size_t)(n0 + r) * K + k0 + sl * 8], &Bs[g * 512]);
        }
    };

    issue(0, 0);

    const int mrow = lane & 15;
    const int kg = lane >> 4;                     // 0..3
    for (int kt = 0; kt < NKT; ++kt) {
        const int cur = kt & 1;
        if (kt + 1 < NKT) {
            issue(kt + 1, cur ^ 1);
            asm volatile("s_waitcnt vmcnt(%0)" :: "n"(VMC) : "memory");
        } else {
            asm volatile("s_waitcnt vmcnt(0)" ::: "memory");
        }
        __builtin_amdgcn_s_barrier();
        __builtin_amdgcn_sched_barrier(0);

        const short* As = smem + cur * HALF;
        const short* Bs = As + BM * BK;
        short8v af[FM], bf[FN];
#pragma unroll
        for (int f = 0; f < FM; ++f) {
            int m = wm * WM + f * 16 + mrow;
            af[f] = *reinterpret_cast<const short8v*>(
                &As[m * 32 + ((kg ^ ((m >> 1) & 3)) << 3)]);
        }
#pragma unroll
        for (int f = 0; f < FN; ++f) {
            int nr = wn * 64 + f * 16 + mrow;
            bf[f] = *reinterpret_cast<const short8v*>(
                &Bs[nr * 32 + ((kg ^ ((nr >> 1) & 3)) << 3)]);
        }
#pragma unroll
        for (int i = 0; i < FM; ++i)
#pragma unroll
            for (int j = 0; j < FN; ++j)
                acc[i][j] = __builtin_amdgcn_mfma_f32_16x16x32_bf16(
                    af[i], bf[j], acc[i][j], 0, 0, 0);

        asm volatile("s_waitcnt lgkmcnt(0)" ::: "memory");
        __builtin_amdgcn_sched_barrier(0);
        __builtin_amdgcn_s_barrier();
    }

    // ---- stage accumulator tile into LDS (bf16) ----
#pragma unroll
    for (int i = 0; i < FM; ++i)
#pragma unroll
        for (int j = 0; j < FN; ++j) {
            int cc = wn * 64 + j * 16 + (lane & 15);
#pragma unroll
            for (int e = 0; e < 4; ++e) {
                int r = wm * WM + i * 16 + (lane >> 4) * 4 + e;
                smem[r * BNout + cc] = f2b(acc[i][j][e]);
            }
        }
    __syncthreads();

    if (bn == 2) {
        constexpr int CH = BM * BNout / 8;
#pragma unroll
        for (int p = 0; p < CH / 256; ++p) {
            int idx = p * 256 + tid;
            int r = idx / (BNout / 8);
            int c8 = idx % (BNout / 8);
            int grow = m0 + r;
            if (grow < M)
                *reinterpret_cast<int4*>(&xm[(size_t)grow * BNout + c8 * 8]) =
                    *reinterpret_cast<const int4*>(&smem[r * BNout + c8 * 8]);
        }
    } else {
#pragma unroll
        for (int p = 0; p < (BM * (HB / 8)) / 256; ++p) {
            int idx = p * 256 + tid;
            int r = idx / (HB / 8);
            int c8 = idx % (HB / 8);
            int grow = m0 + r;
            if (grow < M)
                *reinterpret_cast<int4*>(&xh[(size_t)grow * BNout + bn * HB + c8 * 8]) =
                    *reinterpret_cast<const int4*>(&smem[r * BNout + HB + c8 * 8]);
        }
#pragma unroll
        for (int p = 0; p < (BM * (BNout / 4)) / 256; ++p) {
            int idx = p * 256 + tid;
            int r = idx / (BNout / 4);
            int k = idx % (BNout / 4);
            int grow = m0 + r;
            if (grow < M) {
                unsigned lw = *reinterpret_cast<const unsigned*>(&smem[r * BNout + 2 * k]);
                unsigned hw = *reinterpret_cast<const unsigned*>(&smem[r * BNout + HB + 2 * k]);
                unsigned w;
                if (BNout == 128) {
                    w = __builtin_amdgcn_cvt_pk_fp8_f32(b2f_lo(lw), b2f_hi(lw), 0, false);
                    w = __builtin_amdgcn_cvt_pk_fp8_f32(b2f_lo(hw), b2f_hi(hw), w, true);
                } else {
                    w = __builtin_amdgcn_cvt_pk_fp8_f32(b2f_lo(lw), b2f_lo(hw), 0, false);
                    w = __builtin_amdgcn_cvt_pk_fp8_f32(b2f_hi(lw), b2f_hi(hw), w, true);
                }
                xq[(size_t)grow * (BNout / 2) + bn * (BNout / 4) + k] = w;
            }
        }
    }
}

template <int BNout>
struct GemmSmem {
    static constexpr int SM1 = 2 * (128 * 32 + BNout * 32);
    static constexpr int SM2 = 128 * BNout;
    static constexpr int SZ = SM1 > SM2 ? SM1 : SM2;
};

// ---------------------------------------------------------------------------
// Fused layer-1 GEMM + edge scatter (Bresenham interleave, int2 records)
// ---------------------------------------------------------------------------
template <int K, int BNout>
__global__ __launch_bounds__(256) void gemm_scatter(const short* __restrict__ A,
                                                    const short* __restrict__ Bt,
                                                    unsigned* __restrict__ xq,
                                                    short* __restrict__ xh,
                                                    short* __restrict__ xm,
                                                    int M, int nGemm,
                                                    const int* __restrict__ row,
                                                    const int* __restrict__ col,
                                                    const float* __restrict__ val,
                                                    int* __restrict__ cursor,
                                                    int2* __restrict__ edges, int E,
                                                    int nScat) {
    __shared__ short smem[GemmSmem<BNout>::SZ];

    const int total = nGemm + nScat;
    const int swz = xcd_swz(blockIdx.x, total);
    const long ns_b = ((long)swz * nScat) / total;
    const long ns_a = ((long)(swz + 1) * nScat) / total;

    if (ns_a != ns_b) {
        int i = (int)ns_b * 256 + threadIdx.x;
        if (i < E) {
            int r = row[i];
            int p = atomicAdd(&cursor[r], 1);
            int2 rec;
            rec.x = col[i];
            rec.y = __builtin_bit_cast(int, val[i]);
            edges[p] = rec;
        }
        return;
    }
    gemm_body<K, BNout>(A, Bt, xq, xh, xm, M, swz - (int)ns_b, smem);
}

// ---------------------------------------------------------------------------
// Standalone layer-2 GEMM
// ---------------------------------------------------------------------------
template <int K, int BNout>
__global__ __launch_bounds__(256) void gemm_mfma(const short* __restrict__ A,
                                                 const short* __restrict__ Bt,
                                                 unsigned* __restrict__ xq,
                                                 short* __restrict__ xh,
                                                 short* __restrict__ xm,
                                                 int M) {
    __shared__ short smem[GemmSmem<BNout>::SZ];
    gemm_body<K, BNout>(A, Bt, xq, xh, xm, M, xcd_swz(blockIdx.x, gridDim.x), smem);
}

// ---------------------------------------------------------------------------
// CSR scan chain
// ---------------------------------------------------------------------------
__global__ __launch_bounds__(256) void block_sums_kernel(const int* __restrict__ counts,
                                                         int* __restrict__ bsums, int n) {
    __shared__ int s[256];
    int tid = threadIdx.x;
    int i = blockIdx.x * 256 + tid;
    s[tid] = (i < n) ? counts[i] : 0;
    __syncthreads();
#pragma unroll
    for (int off = 128; off > 0; off >>= 1) {
        if (tid < off) s[tid] += s[tid + off];
        __syncthreads();
    }
    if (tid == 0) bsums[blockIdx.x] = s[0];
}

__global__ __launch_bounds__(256) void scan_bsums_kernel(int* __restrict__ bsums, int nb) {
    __shared__ int s[256];
    int t = threadIdx.x;
    int v = (t < nb) ? bsums[t] : 0;
    s[t] = v;
    __syncthreads();
#pragma unroll
    for (int off = 1; off < 256; off <<= 1) {
        int u = (t >= off) ? s[t - off] : 0;
        __syncthreads();
        s[t] += u;
        __syncthreads();
    }
    if (t < nb) bsums[t] = s[t] - v;      // exclusive
}

__global__ __launch_bounds__(256) void scan_final_kernel(const int* __restrict__ counts,
                                                         const int* __restrict__ bsums,
                                                         int* __restrict__ rowptr,
                                                         int* __restrict__ cursor, int n) {
    __shared__ int s[256];
    int tid = threadIdx.x;
    int i = blockIdx.x * 256 + tid;
    int v = (i < n) ? counts[i] : 0;
    s[tid] = v;
    __syncthreads();
#pragma unroll
    for (int off = 1; off < 256; off <<= 1) {
        int t = (tid >= off) ? s[tid - off] : 0;
        __syncthreads();
        s[tid] += t;
        __syncthreads();
    }
    int excl = s[tid] - v + bsums[blockIdx.x];
    if (i < n) {
        rowptr[i] = excl;
        cursor[i] = excl;
        if (i == n - 1) rowptr[n] = excl + v;
    }
}

// ---------------------------------------------------------------------------
__device__ __forceinline__ float wave_sum(float v) {
#pragma unroll
    for (int off = 32; off > 0; off >>= 1) v += __shfl_xor(v, off, 64);
    return v;
}
__device__ __forceinline__ float wave_max(float v) {
#pragma unroll
    for (int off = 32; off > 0; off >>= 1) v = fmaxf(v, __shfl_xor(v, off, 64));
    return v;
}

// ---------------------------------------------------------------------------
// Layer-1 fused: dual CSR spmm (fp8 gathers, 8-deep pipeline) + attention +
// combine -> h bf16.
// ---------------------------------------------------------------------------
__global__ __launch_bounds__(256) void spmm_att1(const int* __restrict__ rowptr,
                                                 const int2* __restrict__ edges,
                                                 const unsigned* __restrict__ xq,
                                                 const unsigned* __restrict__ xhp,
                                                 const unsigned* __restrict__ xmp,
                                                 const float* __restrict__ a_low,
                                                 const float* __restrict__ a_high,
                                                 const float* __restrict__ a_mlp,
                                                 const float* __restrict__ av,
                                                 short* __restrict__ hb,
                                                 int n) {
    const int node = blockIdx.x * 4 + (threadIdx.x >> 6);
    const int lane = threadIdx.x & 63;
    if (node >= n) return;

    const int s = __builtin_amdgcn_readfirstlane(rowptr[node]);
    const int e = __builtin_amdgcn_readfirstlane(rowptr[node + 1]);

    float l0 = 0.f, l1 = 0.f, h0 = 0.f, h1 = 0.f;
    for (int j = s; j < e; j += 8) {
        int   cq[8];
        float vq[8];
#pragma unroll
        for (int q = 0; q < 8; ++q) {
            const int jj = min(j + q, e - 1);
            const int2 rec = edges[jj];
            cq[q] = __builtin_amdgcn_readfirstlane(rec.x);
            int vb = __builtin_amdgcn_readfirstlane(rec.y);
            float t = __builtin_bit_cast(float, vb);
            vq[q] = (j + q < e) ? t : 0.f;
        }
        unsigned p[8];
#pragma unroll
        for (int q = 0; q < 8; ++q)
            p[q] = xq[(size_t)cq[q] * 64 + lane];      // 8 gathers in flight
#pragma unroll
        for (int q = 0; q < 8; ++q) {
            const f32x2 lo = q2_lo(p[q]);
            const f32x2 hi = q2_hi(p[q]);
            l0 += vq[q] * lo.x; l1 += vq[q] * lo.y;
            h0 += vq[q] * hi.x; h1 += vq[q] * hi.y;
        }
    }

    const unsigned xhn = xhp[(size_t)node * 64 + lane];
    const unsigned xmn = xmp[(size_t)node * 64 + lane];
    float ol0 = fmaxf(l0, 0.f);
    float ol1 = fmaxf(l1, 0.f);
    float oh0 = fmaxf(b2f_lo(xhn) - h0, 0.f);
    float oh1 = fmaxf(b2f_hi(xhn) - h1, 0.f);
    float om0 = fmaxf(b2f_lo(xmn), 0.f);
    float om1 = fmaxf(b2f_hi(xmn), 0.f);

    const float2 aL = ((const float2*)a_low)[lane];
    const float2 aH = ((const float2*)a_high)[lane];
    const float2 aM = ((const float2*)a_mlp)[lane];
    float dl = wave_sum(ol0 * aL.x + ol1 * aL.y);
    float dh = wave_sum(oh0 * aH.x + oh1 * aH.y);
    float dm = wave_sum(om0 * aM.x + om1 * aM.y);

    const float g0 = 1.f / (1.f + expf(-dl));
    const float g1 = 1.f / (1.f + expf(-dh));
    const float g2 = 1.f / (1.f + expf(-dm));
    float s0 = (g0 * av[0] + g1 * av[3] + g2 * av[6]) * (1.f / 3.f);
    float s1 = (g0 * av[1] + g1 * av[4] + g2 * av[7]) * (1.f / 3.f);
    float s2 = (g0 * av[2] + g1 * av[5] + g2 * av[8]) * (1.f / 3.f);
    float mx = fmaxf(s0, fmaxf(s1, s2));
    float e0 = expf(s0 - mx), e1 = expf(s1 - mx), e2 = expf(s2 - mx);
    float inv = 1.f / (e0 + e1 + e2);
    float at0 = e0 * inv, at1 = e1 * inv, at2 = e2 * inv;

    float ho0 = 3.f * (at0 * ol0 + at1 * oh0 + at2 * om0);
    float ho1 = 3.f * (at0 * ol1 + at1 * oh1 + at2 * om1);
    unsigned pk = (unsigned)(unsigned short)f2b(ho0) |
                  ((unsigned)(unsigned short)f2b(ho1) << 16);
    ((unsigned*)hb)[(size_t)node * 64 + lane] = pk;
}

// ---------------------------------------------------------------------------
// Layer-2 fused: dual CSR spmm (fp8 ushort gathers, 8-deep) + attention +
// combine + log_softmax -> out.
// ---------------------------------------------------------------------------
__global__ __launch_bounds__(256) void spmm_att2(const int* __restrict__ rowptr,
                                                 const int2* __restrict__ edges,
                                                 const unsigned short* __restrict__ xq,
                                                 const short* __restrict__ xhp,
                                                 const short* __restrict__ xmp,
                                                 const float* __restrict__ a_low,
                                                 const float* __restrict__ a_high,
                                                 const float* __restrict__ a_mlp,
                                                 const float* __restrict__ av,
                                                 float* __restrict__ out,
                                                 int n) {
    const int node = blockIdx.x * 4 + (threadIdx.x >> 6);
    const int lane = threadIdx.x & 63;
    if (node >= n) return;

    const int s = __builtin_amdgcn_readfirstlane(rowptr[node]);
    const int e = __builtin_amdgcn_readfirstlane(rowptr[node + 1]);

    float accl = 0.f, acch = 0.f;
    for (int j = s; j < e; j += 8) {
        int   cq[8];
        float vq[8];
#pragma unroll
        for (int q = 0; q < 8; ++q) {
            const int jj = min(j + q, e - 1);
            const int2 rec = edges[jj];
            cq[q] = __builtin_amdgcn_readfirstlane(rec.x);
            int vb = __builtin_amdgcn_readfirstlane(rec.y);
            float t = __builtin_bit_cast(float, vb);
            vq[q] = (j + q < e) ? t : 0.f;
        }
        unsigned short p[8];
#pragma unroll
        for (int q = 0; q < 8; ++q)
            p[q] = xq[(size_t)cq[q] * 64 + lane];
#pragma unroll
        for (int q = 0; q < 8; ++q) {
            const f32x2 d = q2_lo((unsigned)p[q]);
            accl += vq[q] * d.x;
            acch += vq[q] * d.y;
        }
    }

    float ol = fmaxf(accl, 0.f);
    float oh = fmaxf(b2f(xhp[(size_t)node * 64 + lane]) - acch, 0.f);
    float om = fmaxf(b2f(xmp[(size_t)node * 64 + lane]), 0.f);

    float dl = wave_sum(ol * a_low[lane]);
    float dh = wave_sum(oh * a_high[lane]);
    float dm = wave_sum(om * a_mlp[lane]);

    const float g0 = 1.f / (1.f + expf(-dl));
    const float g1 = 1.f / (1.f + expf(-dh));
    const float g2 = 1.f / (1.f + expf(-dm));
    float s0 = (g0 * av[0] + g1 * av[3] + g2 * av[6]) * (1.f / 3.f);
    float s1 = (g0 * av[1] + g1 * av[4] + g2 * av[7]) * (1.f / 3.f);
    float s2 = (g0 * av[2] + g1 * av[5] + g2 * av[8]) * (1.f / 3.f);
    float mx3 = fmaxf(s0, fmaxf(s1, s2));
    float e0 = expf(s0 - mx3), e1 = expf(s1 - mx3), e2 = expf(s2 - mx3);
    float inv = 1.f / (e0 + e1 + e2);
    float at0 = e0 * inv, at1 = e1 * inv, at2 = e2 * inv;

    float o = 3.f * (at0 * ol + at1 * oh + at2 * om);

    float m = wave_max(o);
    float ex = expf(o - m);
    float su = wave_sum(ex);
    out[(size_t)node * 64 + lane] = o - m - logf(su);
}

// ---------------------------------------------------------------------------
extern "C" void kernel_launch(void* const* d_in, const int* in_sizes, int n_in,
                              void* d_out, int out_size, void* d_ws, size_t ws_size,
                              hipStream_t stream) {
    const float* x    = (const float*)d_in[0];
    const int*   erow = (const int*)d_in[1];
    const int*   ecol = (const int*)d_in[2];
    const float* eval = (const float*)d_in[3];
    const float* Wl   = (const float*)d_in[4];
    const float* Wh   = (const float*)d_in[5];
    const float* Wm   = (const float*)d_in[6];
    const float* al   = (const float*)d_in[7];
    const float* ah   = (const float*)d_in[8];
    const float* am   = (const float*)d_in[9];
    const float* av   = (const float*)d_in[10];
    const float* Wl2  = (const float*)d_in[11];
    const float* Wh2  = (const float*)d_in[12];
    const float* Wm2  = (const float*)d_in[13];
    const float* al2  = (const float*)d_in[14];
    const float* ah2  = (const float*)d_in[15];
    const float* am2  = (const float*)d_in[16];
    const float* av2  = (const float*)d_in[17];
    float* out = (float*)d_out;

    const int E = in_sizes[1];
    const int N = NN;

    short* ws    = (short*)d_ws;
    short* xb    = ws;                          // N*512 bf16 (converted x)
    short* xh1   = xb + (size_t)N * 512;        // N*128 bf16 plane
    short* xm1   = xh1 + (size_t)N * 128;       // N*128 bf16 plane
    short* hb    = xm1 + (size_t)N * 128;       // N*128 bf16
    unsigned* xq1 = (unsigned*)(hb + (size_t)N * 128);   // N*64 dwords (12.8 MB)
    short* Bt1   = (short*)(xq1 + (size_t)N * 64);       // 384*512
    short* Bt2   = Bt1 + 384 * 512;             // 192*128
    int*   ip    = (int*)(Bt2 + 192 * 128);
    int*   counts = ip;                         // N
    int*   rowptr = ip + N;                     // N+1
    int*   cursor = ip + 2 * N + 1;             // N
    int*   bsums  = ip + 3 * N + 1;             // 256
    int2*  edges  = (int2*)(((size_t)(ip + 3 * N + 1 + 256) + 15) & ~(size_t)15); // E int2

    // Layer-2 aliases (xh1/xm1/xq1 dead after spmm_att1)
    unsigned* xq2 = xq1;                        // N*32 dwords (N*64 fp8 ushorts)
    short* xh2 = xh1;                           // N*64 bf16
    short* xm2 = xh1 + (size_t)N * 64;          // N*64 bf16

    const int NB = (N + 255) / 256;
    const int EB = (E + 255) / 256;
    const int node_blocks = (N + 3) / 4;
    const int MT = (N + 127) / 128;
    const int XCB = (N * F_IN / 8 + 255) / 256;
    const int W1B = (3 * HH * (F_IN / 8) + 255) / 256;
    const int W2B = (3 * CC * (HH / 8) + 255) / 256;
    const int nGemm1 = MT * 3;

    // ---------------- prep (fused) + CSR scan chain ----------------
    prep0<<<NB + W1B + W2B, 256, 0, stream>>>(counts, N, Wl, Wh, Wm, Bt1,
                                              Wl2, Wh2, Wm2, Bt2, NB, W1B);
    hist_xconv<<<EB + XCB, 256, 0, stream>>>(erow, counts, E, x, xb,
                                             N * F_IN / 8, EB);
    block_sums_kernel<<<NB, 256, 0, stream>>>(counts, bsums, N);
    scan_bsums_kernel<<<1, 256, 0, stream>>>(bsums, NB);
    scan_final_kernel<<<NB, 256, 0, stream>>>(counts, bsums, rowptr, cursor, N);

    // ---------------- Layer 1 (gemm interleaved with edge scatter) ----------
    gemm_scatter<F_IN, HH><<<nGemm1 + EB, 256, 0, stream>>>(
        xb, Bt1, xq1, xh1, xm1, N, nGemm1, erow, ecol, eval, cursor, edges, E, EB);
    spmm_att1<<<node_blocks, 256, 0, stream>>>(rowptr, edges, xq1,
                                               (const unsigned*)xh1,
                                               (const unsigned*)xm1,
                                               al, ah, am, av, hb, N);

    // ---------------- Layer 2 ----------------
    gemm_mfma<HH, CC><<<MT * 3, 256, 0, stream>>>(hb, Bt2, xq2, xh2, xm2, N);
    spmm_att2<<<node_blocks, 256, 0, stream>>>(rowptr, edges,
                                               (const unsigned short*)xq2,
                                               xh2, xm2,
                                               al2, ah2, am2, av2, out, N);
}